// Round 1
// baseline (537.989 us; speedup 1.0000x reference)
//
#include <hip/hip_runtime.h>

#define T_DIM 2048
#define H_DIM 256
#define B_DIM 64
#define CHUNK 128
#define NCH (T_DIM / CHUNK)   /* 16 chunks per batch row */
#define NCB (B_DIM * NCH)     /* 1024 blocks */
#define EPS_F 1e-4f

// Compute mu and inv-sd (= 1/max(sqrt(var),EPS)) from window sums.
__device__ __forceinline__ void win_stats(float s1, float s2, float inv_w, float inv_wm1,
                                          float& mu, float& isd) {
    mu = s1 * inv_w;
    float var = fmaxf((s2 - s1 * s1 * inv_w) * inv_wm1, 0.0f);
    // 1/max(sqrt(var),1e-4) == min(rsqrt(var), 1e4); rsqrt(0)=inf -> 1e4. Matches ref.
    isd = fminf(rsqrtf(var), 1e4f);
}

// PASS 0: compute FAN, accumulate per-(slice,h) sum/sumsq partials.
// PASS 1: recompute FAN identically, finalize slice stats, apply SAN + residual, write out.
template <int PASS>
__global__ __launch_bounds__(256)
void fan_kernel(const float* __restrict__ x, const float* __restrict__ alpha,
                const float* __restrict__ gamma, const float* __restrict__ beta,
                float* __restrict__ part, const float* __restrict__ acc,
                float* __restrict__ out) {
    const int blk = blockIdx.x;
    const int b = blk / NCH;
    const int c = blk % NCH;
    const int h = threadIdx.x;
    const int t0 = c * CHUNK;
    const float* xbh = x + (size_t)b * T_DIM * H_DIM + h;   // element t at xbh[t*H_DIM]

    // softmax over alpha[h][0..2]
    const float a0 = alpha[h * 3 + 0], a1 = alpha[h * 3 + 1], a2 = alpha[h * 3 + 2];
    const float mx = fmaxf(a0, fmaxf(a1, a2));
    const float e0 = __expf(a0 - mx), e1 = __expf(a1 - mx), e2 = __expf(a2 - mx);
    const float einv = 1.0f / (e0 + e1 + e2);
    const float al0 = e0 * einv, al1 = e1 * einv, al2 = e2 * einv;

    // PASS1: finalize per-slice stats (N0 = 64*1536, N1 = 64*1024)
    float mu0 = 0.f, isd0 = 0.f, g0 = 0.f, be0 = 0.f;
    float mu1 = 0.f, isd1 = 0.f, g1 = 0.f, be1 = 0.f;
    if (PASS == 1) {
        const float N0 = 64.0f * 1536.0f, N1 = 64.0f * 1024.0f;
        float S10 = acc[0 * H_DIM + h], S20 = acc[1 * H_DIM + h];
        float S11 = acc[2 * H_DIM + h], S21 = acc[3 * H_DIM + h];
        mu0 = S10 / N0;
        float v0 = fmaxf((S20 - S10 * S10 / N0) / (N0 - 1.0f), 0.0f);
        isd0 = 1.0f / fmaxf(sqrtf(v0), EPS_F);
        mu1 = S11 / N1;
        float v1 = fmaxf((S21 - S11 * S11 / N1) / (N1 - 1.0f), 0.0f);
        isd1 = 1.0f / fmaxf(sqrtf(v1), EPS_F);
        g0 = gamma[0 * H_DIM + h]; be0 = beta[0 * H_DIM + h];
        g1 = gamma[1 * H_DIM + h]; be1 = beta[1 * H_DIM + h];
    }

    // Rolling window state
    float s1_5 = 0.f, s2_5 = 0.f, s1_10 = 0.f, s2_10 = 0.f, s1_20 = 0.f, s2_20 = 0.f;
    float mu5i = 0.f, isd5i = 0.f, mu10i = 0.f, isd10i = 0.f, mu20i = 0.f, isd20i = 0.f;
    const bool first = (c == 0);

    if (first) {
        // Edge stats: windows [0,w) for t < w-1 (reference's edge-pad semantics).
        float c1 = 0.f, c2 = 0.f;
#pragma unroll
        for (int j = 0; j < 20; ++j) {
            float v = xbh[j * H_DIM];
            c1 += v; c2 += v * v;
            if (j == 4)  win_stats(c1, c2, 0.2f,  0.25f,        mu5i,  isd5i);
            if (j == 9)  win_stats(c1, c2, 0.1f,  1.f / 9.f,    mu10i, isd10i);
            if (j == 19) win_stats(c1, c2, 0.05f, 1.f / 19.f,   mu20i, isd20i);
        }
    } else {
        // Warm-up: window sums covering [t0-w, t0)
#pragma unroll
        for (int j = -20; j < 0; ++j) {
            float v = xbh[(t0 + j) * H_DIM];
            s1_20 += v; s2_20 += v * v;
            if (j >= -10) { s1_10 += v; s2_10 += v * v; }
            if (j >= -5)  { s1_5  += v; s2_5  += v * v; }
        }
    }

    float ls1 = 0.0f, ls2 = 0.0f;   // PASS0 slice accumulators

#pragma unroll 4
    for (int i = 0; i < CHUNK; ++i) {
        const int t = t0 + i;
        const float v = xbh[t * H_DIM];
        s1_5  += v; s2_5  += v * v;
        s1_10 += v; s2_10 += v * v;
        s1_20 += v; s2_20 += v * v;
        if (!first || t >= 5)  { float o = xbh[(t - 5)  * H_DIM]; s1_5  -= o; s2_5  -= o * o; }
        if (!first || t >= 10) { float o = xbh[(t - 10) * H_DIM]; s1_10 -= o; s2_10 -= o * o; }
        if (!first || t >= 20) { float o = xbh[(t - 20) * H_DIM]; s1_20 -= o; s2_20 -= o * o; }

        float mu, isd, fan = 0.0f;
        if (!first || t >= 4)  win_stats(s1_5,  s2_5,  0.2f,  0.25f,      mu, isd);
        else { mu = mu5i;  isd = isd5i; }
        fan += (v - mu) * isd * al0;
        if (!first || t >= 9)  win_stats(s1_10, s2_10, 0.1f,  1.f / 9.f,  mu, isd);
        else { mu = mu10i; isd = isd10i; }
        fan += (v - mu) * isd * al1;
        if (!first || t >= 19) win_stats(s1_20, s2_20, 0.05f, 1.f / 19.f, mu, isd);
        else { mu = mu20i; isd = isd20i; }
        fan += (v - mu) * isd * al2;

        if (PASS == 0) {
            ls1 += fan; ls2 += fan * fan;
        } else {
            // SAN: slice0 = [0,1536), slice1 = [1024,2048); cnt normalization 1/(cnt+1e-4)
            float z0 = (fan - mu0) * isd0 * g0 + be0;
            float z1 = (fan - mu1) * isd1 * g1 + be1;
            float y;
            if (t < 1024)       y = z0 * (1.0f / 1.0001f);
            else if (t >= 1536) y = z1 * (1.0f / 1.0001f);
            else                y = (z0 + z1) * (1.0f / 2.0001f);
            out[(size_t)(b * T_DIM + t) * H_DIM + h] = v + y;
        }
    }

    if (PASS == 0) {
        // slice membership is chunk-aligned: slice0 iff c<12, slice1 iff c>=8
        const bool in0 = (c < 12), in1 = (c >= 8);
        part[(0 * NCB + blk) * H_DIM + h] = in0 ? ls1 : 0.0f;
        part[(1 * NCB + blk) * H_DIM + h] = in0 ? ls2 : 0.0f;
        part[(2 * NCB + blk) * H_DIM + h] = in1 ? ls1 : 0.0f;
        part[(3 * NCB + blk) * H_DIM + h] = in1 ? ls2 : 0.0f;
    }
}

// 32 blocks: (slice k, group g of 64 chunk-blocks) -> atomicAdd into acc[4][256]
__global__ __launch_bounds__(256)
void reduce_kernel(const float* __restrict__ part, float* __restrict__ acc) {
    const int h = threadIdx.x;
    const int k = blockIdx.x >> 4;     // slice 0/1
    const int g = blockIdx.x & 15;
    float a1 = 0.f, a2 = 0.f;
    for (int i = 0; i < NCB / 16; ++i) {
        const int cb = g * (NCB / 16) + i;
        a1 += part[((2 * k)     * NCB + cb) * H_DIM + h];
        a2 += part[((2 * k + 1) * NCB + cb) * H_DIM + h];
    }
    atomicAdd(&acc[(2 * k)     * H_DIM + h], a1);
    atomicAdd(&acc[(2 * k + 1) * H_DIM + h], a2);
}

extern "C" void kernel_launch(void* const* d_in, const int* in_sizes, int n_in,
                              void* d_out, int out_size, void* d_ws, size_t ws_size,
                              hipStream_t stream) {
    const float* x     = (const float*)d_in[0];
    const float* alpha = (const float*)d_in[1];
    const float* gamma = (const float*)d_in[2];
    const float* beta  = (const float*)d_in[3];
    float* out  = (float*)d_out;
    float* part = (float*)d_ws;                       // 4*NCB*H_DIM floats = 4 MB
    float* acc  = part + 4 * NCB * H_DIM;             // 4*H_DIM floats = 4 KB

    hipMemsetAsync(acc, 0, 4 * H_DIM * sizeof(float), stream);
    fan_kernel<0><<<NCB, H_DIM, 0, stream>>>(x, alpha, gamma, beta, part, acc, out);
    reduce_kernel<<<32, H_DIM, 0, stream>>>(part, acc);
    fan_kernel<1><<<NCB, H_DIM, 0, stream>>>(x, alpha, gamma, beta, part, acc, out);
}

// Round 2
// 386.946 us; speedup vs baseline: 1.3903x; 1.3903x over previous
//
#include <hip/hip_runtime.h>

#define T_DIM 2048
#define H_DIM 256
#define B_DIM 64
#define CHUNK 128
#define NCH (T_DIM / CHUNK)   /* 16 chunks per batch row */
#define NCB (B_DIM * NCH)     /* 1024 blocks */
#define EPS_F 1e-4f

// Compute mu and inv-sd (= 1/max(sqrt(var),EPS)) from window sums.
__device__ __forceinline__ void win_stats(float s1, float s2, float inv_w, float inv_wm1,
                                          float& mu, float& isd) {
    mu = s1 * inv_w;
    float var = fmaxf((s2 - s1 * s1 * inv_w) * inv_wm1, 0.0f);
    // 1/max(sqrt(var),1e-4) == min(rsqrt(var), 1e4); rsqrt(0)=inf -> 1e4. Matches ref.
    isd = fminf(rsqrtf(var), 1e4f);
}

// PASS 0: compute FAN, accumulate per-(slice,h) sum/sumsq partials.
// PASS 1: recompute FAN identically, finalize slice stats, apply SAN + residual, write out.
// Register delay line (hist[32], unroll 32 -> static indices) gives 1 global load
// per element instead of 4 and 32 independent loads in flight per group.
template <int PASS>
__global__ __launch_bounds__(256)
void fan_kernel(const float* __restrict__ x, const float* __restrict__ alpha,
                const float* __restrict__ gamma, const float* __restrict__ beta,
                float* __restrict__ part, const float* __restrict__ acc,
                float* __restrict__ out) {
    const int blk = blockIdx.x;
    const int b = blk / NCH;
    const int c = blk % NCH;
    const int h = threadIdx.x;
    const int t0 = c * CHUNK;
    const float* xbh = x + (size_t)b * T_DIM * H_DIM + h;   // element t at xbh[t*H_DIM]

    // softmax over alpha[h][0..2]
    const float a0 = alpha[h * 3 + 0], a1 = alpha[h * 3 + 1], a2 = alpha[h * 3 + 2];
    const float mx = fmaxf(a0, fmaxf(a1, a2));
    const float e0 = __expf(a0 - mx), e1 = __expf(a1 - mx), e2 = __expf(a2 - mx);
    const float einv = 1.0f / (e0 + e1 + e2);
    const float al0 = e0 * einv, al1 = e1 * einv, al2 = e2 * einv;

    // PASS1: finalize per-slice stats (N0 = 64*1536, N1 = 64*1024)
    float mu0 = 0.f, isd0 = 0.f, g0 = 0.f, be0 = 0.f;
    float mu1 = 0.f, isd1 = 0.f, g1 = 0.f, be1 = 0.f;
    if (PASS == 1) {
        const float N0 = 64.0f * 1536.0f, N1 = 64.0f * 1024.0f;
        float S10 = acc[0 * H_DIM + h], S20 = acc[1 * H_DIM + h];
        float S11 = acc[2 * H_DIM + h], S21 = acc[3 * H_DIM + h];
        mu0 = S10 / N0;
        float v0 = fmaxf((S20 - S10 * S10 / N0) / (N0 - 1.0f), 0.0f);
        isd0 = 1.0f / fmaxf(sqrtf(v0), EPS_F);
        mu1 = S11 / N1;
        float v1 = fmaxf((S21 - S11 * S11 / N1) / (N1 - 1.0f), 0.0f);
        isd1 = 1.0f / fmaxf(sqrtf(v1), EPS_F);
        g0 = gamma[0 * H_DIM + h]; be0 = beta[0 * H_DIM + h];
        g1 = gamma[1 * H_DIM + h]; be1 = beta[1 * H_DIM + h];
    }

    // Rolling window state
    float s1_5 = 0.f, s2_5 = 0.f, s1_10 = 0.f, s2_10 = 0.f, s1_20 = 0.f, s2_20 = 0.f;
    float mu5i = 0.f, isd5i = 0.f, mu10i = 0.f, isd10i = 0.f, mu20i = 0.f, isd20i = 0.f;
    const bool first = (c == 0);

    float hist[32];

    if (first) {
        // Edge stats: windows [0,w) for t < w-1 (reference's edge-pad semantics).
        float c1 = 0.f, c2 = 0.f;
#pragma unroll
        for (int j = 0; j < 20; ++j) {
            float v = xbh[j * H_DIM];
            c1 += v; c2 += v * v;
            if (j == 4)  win_stats(c1, c2, 0.2f,  0.25f,        mu5i,  isd5i);
            if (j == 9)  win_stats(c1, c2, 0.1f,  1.f / 9.f,    mu10i, isd10i);
            if (j == 19) win_stats(c1, c2, 0.05f, 1.f / 19.f,   mu20i, isd20i);
        }
        // hist preload unused for first chunk (guards cover t<w), but keep defined.
#pragma unroll
        for (int j = 0; j < 32; ++j) hist[j] = 0.0f;
    } else {
        // Warm-up: window sums covering [t0-w, t0); fill delay line positions 12..31.
#pragma unroll
        for (int j = 1; j <= 20; ++j) {
            float v = xbh[(t0 - j) * H_DIM];
            hist[(32 - j) & 31] = v;
            s1_20 += v; s2_20 += v * v;
            if (j <= 10) { s1_10 += v; s2_10 += v * v; }
            if (j <= 5)  { s1_5  += v; s2_5  += v * v; }
        }
#pragma unroll
        for (int j = 0; j < 12; ++j) hist[j] = 0.0f;
    }

    float ls1 = 0.0f, ls2 = 0.0f;   // PASS0 slice accumulators

    for (int i0 = 0; i0 < CHUNK; i0 += 32) {
#pragma unroll
        for (int k = 0; k < 32; ++k) {
            const int t = t0 + i0 + k;
            const float v = xbh[t * H_DIM];
            hist[k] = v;                       // (i0+k)&31 == k since i0 % 32 == 0
            s1_5  += v; s2_5  += v * v;
            s1_10 += v; s2_10 += v * v;
            s1_20 += v; s2_20 += v * v;
            if (!first || t >= 5)  { float o = hist[(k - 5)  & 31]; s1_5  -= o; s2_5  -= o * o; }
            if (!first || t >= 10) { float o = hist[(k - 10) & 31]; s1_10 -= o; s2_10 -= o * o; }
            if (!first || t >= 20) { float o = hist[(k - 20) & 31]; s1_20 -= o; s2_20 -= o * o; }

            float mu, isd, fan = 0.0f;
            if (!first || t >= 4)  win_stats(s1_5,  s2_5,  0.2f,  0.25f,      mu, isd);
            else { mu = mu5i;  isd = isd5i; }
            fan += (v - mu) * isd * al0;
            if (!first || t >= 9)  win_stats(s1_10, s2_10, 0.1f,  1.f / 9.f,  mu, isd);
            else { mu = mu10i; isd = isd10i; }
            fan += (v - mu) * isd * al1;
            if (!first || t >= 19) win_stats(s1_20, s2_20, 0.05f, 1.f / 19.f, mu, isd);
            else { mu = mu20i; isd = isd20i; }
            fan += (v - mu) * isd * al2;

            if (PASS == 0) {
                ls1 += fan; ls2 += fan * fan;
            } else {
                // SAN: slice0 = [0,1536), slice1 = [1024,2048); cnt norm 1/(cnt+1e-4)
                float z0 = (fan - mu0) * isd0 * g0 + be0;
                float z1 = (fan - mu1) * isd1 * g1 + be1;
                float y;
                if (t < 1024)       y = z0 * (1.0f / 1.0001f);
                else if (t >= 1536) y = z1 * (1.0f / 1.0001f);
                else                y = (z0 + z1) * (1.0f / 2.0001f);
                out[(size_t)(b * T_DIM + t) * H_DIM + h] = v + y;
            }
        }
    }

    if (PASS == 0) {
        // slice membership is chunk-aligned: slice0 iff c<12, slice1 iff c>=8
        const bool in0 = (c < 12), in1 = (c >= 8);
        part[(0 * NCB + blk) * H_DIM + h] = in0 ? ls1 : 0.0f;
        part[(1 * NCB + blk) * H_DIM + h] = in0 ? ls2 : 0.0f;
        part[(2 * NCB + blk) * H_DIM + h] = in1 ? ls1 : 0.0f;
        part[(3 * NCB + blk) * H_DIM + h] = in1 ? ls2 : 0.0f;
    }
}

// 32 blocks: (slice k, group g of 64 chunk-blocks) -> atomicAdd into acc[4][256]
__global__ __launch_bounds__(256)
void reduce_kernel(const float* __restrict__ part, float* __restrict__ acc) {
    const int h = threadIdx.x;
    const int k = blockIdx.x >> 4;     // slice 0/1
    const int g = blockIdx.x & 15;
    float a1 = 0.f, a2 = 0.f;
    for (int i = 0; i < NCB / 16; ++i) {
        const int cb = g * (NCB / 16) + i;
        a1 += part[((2 * k)     * NCB + cb) * H_DIM + h];
        a2 += part[((2 * k + 1) * NCB + cb) * H_DIM + h];
    }
    atomicAdd(&acc[(2 * k)     * H_DIM + h], a1);
    atomicAdd(&acc[(2 * k + 1) * H_DIM + h], a2);
}

extern "C" void kernel_launch(void* const* d_in, const int* in_sizes, int n_in,
                              void* d_out, int out_size, void* d_ws, size_t ws_size,
                              hipStream_t stream) {
    const float* x     = (const float*)d_in[0];
    const float* alpha = (const float*)d_in[1];
    const float* gamma = (const float*)d_in[2];
    const float* beta  = (const float*)d_in[3];
    float* out  = (float*)d_out;
    float* part = (float*)d_ws;                       // 4*NCB*H_DIM floats = 4 MB
    float* acc  = part + 4 * NCB * H_DIM;             // 4*H_DIM floats = 4 KB

    hipMemsetAsync(acc, 0, 4 * H_DIM * sizeof(float), stream);
    fan_kernel<0><<<NCB, H_DIM, 0, stream>>>(x, alpha, gamma, beta, part, acc, out);
    reduce_kernel<<<32, H_DIM, 0, stream>>>(part, acc);
    fan_kernel<1><<<NCB, H_DIM, 0, stream>>>(x, alpha, gamma, beta, part, acc, out);
}